// Round 18
// baseline (139.990 us; speedup 1.0000x reference)
//
#include <hip/hip_runtime.h>
#include <hip/hip_bf16.h>
#include <math.h>

// ---------------------------------------------------------------------------
#define B 8
#define NP 1000
#define NK 56
#define DP 768
#define DV 43
#define DD 256
#define NT 999

typedef __attribute__((ext_vector_type(8))) short bf16x8;
typedef __attribute__((ext_vector_type(4))) float f32x4;

__device__ inline short f2bf(float x) {
    __hip_bfloat16 h = __float2bfloat16(x);
    return __builtin_bit_cast(short, h);
}

// ---------------------------------------------------------------------------
// MFMA GEMM body, full-width N=256 tile (A read exactly once), A-prefetch.
template<bool RELU_IN>
__device__ __forceinline__ void gemm_body256(
    const float* __restrict__ A, const short* __restrict__ Wb,
    const float* __restrict__ bias, float* __restrict__ C,
    int K, int bm, int tid) {
    const int N = DD;
    int lane = tid & 63, w = tid >> 6;
    int m0 = bm * 32 + (w >> 1) * 16;
    int n0 = (w & 1) * 128;
    int lrow = lane & 15, lk = lane >> 4;
    f32x4 acc[8];
    #pragma unroll
    for (int nt = 0; nt < 8; ++nt) acc[nt] = {0.f, 0.f, 0.f, 0.f};
    const float* arow = A + (size_t)(m0 + lrow) * K + lk * 8;
    f32x4 a0 = *reinterpret_cast<const f32x4*>(arow);
    f32x4 a1 = *reinterpret_cast<const f32x4*>(arow + 4);
    for (int k0 = 0; k0 < K; k0 += 32) {
        f32x4 c0 = a0, c1 = a1;
        if (k0 + 32 < K) {
            a0 = *reinterpret_cast<const f32x4*>(arow + k0 + 32);
            a1 = *reinterpret_cast<const f32x4*>(arow + k0 + 36);
        }
        bf16x8 af;
        #pragma unroll
        for (int e = 0; e < 4; ++e) {
            float v0 = c0[e], v1 = c1[e];
            if (RELU_IN) { v0 = fmaxf(v0, 0.f); v1 = fmaxf(v1, 0.f); }
            af[e] = f2bf(v0); af[4 + e] = f2bf(v1);
        }
        const short* bbase = Wb + ((size_t)((k0 >> 3) + lk) * N + n0 + lrow) * 8;
        #pragma unroll
        for (int nt = 0; nt < 8; ++nt) {
            bf16x8 bf = *reinterpret_cast<const bf16x8*>(bbase + nt * 128);
            acc[nt] = __builtin_amdgcn_mfma_f32_16x16x32_bf16(af, bf, acc[nt], 0, 0, 0);
        }
    }
    #pragma unroll
    for (int nt = 0; nt < 8; ++nt) {
        int col = n0 + nt * 16 + lrow;
        float bv = bias[col];
        #pragma unroll
        for (int r = 0; r < 4; ++r) {
            int row = m0 + lk * 4 + r;
            C[(size_t)row * N + col] = acc[nt][r] + bv;
        }
    }
}

// GCN layer body
__device__ __forceinline__ void gcn_layer_body(
    const float* __restrict__ x, const float* __restrict__ adj,
    const float* __restrict__ W, const float* __restrict__ bias,
    float* __restrict__ y, int KIN, int bi, int tid,
    float* arow, float* u) {
    int b = bi / NK, i = bi % NK;
    if (tid < NK) arow[tid] = adj[((size_t)b * NK + i) * NK + tid];
    __syncthreads();
    if (tid < KIN) {
        float a0 = 0.f, a1 = 0.f;
        for (int j = 0; j < NK; j += 2) {
            a0 = fmaf(arow[j],     x[((size_t)b * NK + j)     * KIN + tid], a0);
            a1 = fmaf(arow[j + 1], x[((size_t)b * NK + j + 1) * KIN + tid], a1);
        }
        u[tid] = a0 + a1;
    }
    float rs = 0.f;
    for (int j = 0; j < NK; ++j) rs += arow[j];
    __syncthreads();
    float a0 = 0.f, a1 = 0.f, a2 = 0.f, a3 = 0.f;
    int kk = 0;
    for (; kk + 4 <= KIN; kk += 4) {
        a0 = fmaf(u[kk],     W[(size_t)kk * DD + tid],       a0);
        a1 = fmaf(u[kk + 1], W[(size_t)(kk + 1) * DD + tid], a1);
        a2 = fmaf(u[kk + 2], W[(size_t)(kk + 2) * DD + tid], a2);
        a3 = fmaf(u[kk + 3], W[(size_t)(kk + 3) * DD + tid], a3);
    }
    for (; kk < KIN; ++kk) a0 = fmaf(u[kk], W[(size_t)kk * DD + tid], a0);
    float v = a0 + a1 + a2 + a3 + rs * bias[tid];
    y[((size_t)b * NK + i) * DD + tid] = fmaxf(v, 0.f);
}

// GCN tail body: layer2 -> comp -> qc (qc emitted bf16 in Wb-swizzled layout)
__device__ __forceinline__ void gcn_tail_body(
    const float* __restrict__ y1, const float* __restrict__ adj,
    const float* __restrict__ W2, const float* __restrict__ b2,
    const float* __restrict__ Wf, const float* __restrict__ bf,
    const float* __restrict__ Wjc, const float* __restrict__ bjc,
    float* __restrict__ comp, short* __restrict__ qcb,
    int bi, int tid, float* arow, float* u) {
    int b = bi / NK, i = bi % NK;
    if (tid < NK) arow[tid] = adj[((size_t)b * NK + i) * NK + tid];
    __syncthreads();
    {
        float a0 = 0.f, a1 = 0.f;
        for (int j = 0; j < NK; j += 2) {
            a0 = fmaf(arow[j],     y1[((size_t)b * NK + j)     * DD + tid], a0);
            a1 = fmaf(arow[j + 1], y1[((size_t)b * NK + j + 1) * DD + tid], a1);
        }
        u[tid] = a0 + a1;
    }
    float rs = 0.f;
    for (int j = 0; j < NK; ++j) rs += arow[j];
    __syncthreads();
    float a0 = 0.f, a1 = 0.f, a2 = 0.f, a3 = 0.f;
    #pragma unroll 4
    for (int kk = 0; kk < DD; kk += 4) {
        a0 = fmaf(u[kk],     W2[(size_t)kk * DD + tid],       a0);
        a1 = fmaf(u[kk + 1], W2[(size_t)(kk + 1) * DD + tid], a1);
        a2 = fmaf(u[kk + 2], W2[(size_t)(kk + 2) * DD + tid], a2);
        a3 = fmaf(u[kk + 3], W2[(size_t)(kk + 3) * DD + tid], a3);
    }
    float y2 = fmaxf(a0 + a1 + a2 + a3 + rs * b2[tid], 0.f);
    __syncthreads();
    u[tid] = y2;
    __syncthreads();
    a0 = a1 = a2 = a3 = 0.f;
    #pragma unroll 4
    for (int kk = 0; kk < DD; kk += 4) {
        a0 = fmaf(u[kk],     Wf[(size_t)kk * DD + tid],       a0);
        a1 = fmaf(u[kk + 1], Wf[(size_t)(kk + 1) * DD + tid], a1);
        a2 = fmaf(u[kk + 2], Wf[(size_t)(kk + 2) * DD + tid], a2);
        a3 = fmaf(u[kk + 3], Wf[(size_t)(kk + 3) * DD + tid], a3);
    }
    float cv = a0 + a1 + a2 + a3 + bf[tid];
    comp[((size_t)b * NK + i) * DD + tid] = cv;
    __syncthreads();
    u[tid] = fmaxf(cv, 0.f);
    __syncthreads();
    a0 = a1 = a2 = a3 = 0.f;
    #pragma unroll 4
    for (int kk = 0; kk < DD; kk += 4) {
        a0 = fmaf(u[kk],     Wjc[(size_t)kk * DD + tid],       a0);
        a1 = fmaf(u[kk + 1], Wjc[(size_t)(kk + 1) * DD + tid], a1);
        a2 = fmaf(u[kk + 2], Wjc[(size_t)(kk + 2) * DD + tid], a2);
        a3 = fmaf(u[kk + 3], Wjc[(size_t)(kk + 3) * DD + tid], a3);
    }
    float qv = a0 + a1 + a2 + a3 + bjc[tid];
    qcb[(((size_t)b * 32 + (tid >> 3)) * 64 + i) * 8 + (tid & 7)] = f2bf(qv);
}

// ---------------------------------------------------------------------------
// K1: prep (wcvt x2, fusedcvt, zero regions incl. qcb) + gcn_layer0. Grid 1381.
__global__ __launch_bounds__(256) void k1_kernel(
    const float* __restrict__ W_prot, short* __restrict__ Wb1,
    const float* __restrict__ Wjp, short* __restrict__ Wb2,
    const float* __restrict__ fusedM, short* __restrict__ fMb,
    float* __restrict__ zero_region, float* __restrict__ qcb_zero,
    const float* __restrict__ drug_ver, const float* __restrict__ adj,
    const float* __restrict__ W0, const float* __restrict__ b0,
    float* __restrict__ y0) {
    __shared__ float smem[2112];
    int blk = blockIdx.x, tid = threadIdx.x;
    if (blk < 96) {
        int idx = blk * 256 + tid;
        int koct = idx / DD, n = idx % DD;
        bf16x8 v;
        #pragma unroll
        for (int e = 0; e < 8; ++e)
            v[e] = f2bf(W_prot[(size_t)(koct * 8 + e) * DD + n]);
        *reinterpret_cast<bf16x8*>(Wb1 + (size_t)idx * 8) = v;
    } else if (blk < 128) {
        int idx = (blk - 96) * 256 + tid;
        int koct = idx / DD, n = idx % DD;
        bf16x8 v;
        #pragma unroll
        for (int e = 0; e < 8; ++e)
            v[e] = f2bf(Wjp[(size_t)(koct * 8 + e) * DD + n]);
        *reinterpret_cast<bf16x8*>(Wb2 + (size_t)idx * 8) = v;
    } else if (blk < 640) {
        int blk2 = blk - 128;
        int t0 = (blk2 >> 3) * 16;
        int i0 = (blk2 & 7) * 128;
        for (int l = tid; l < 16 * 128; l += 256) {
            int tt = l >> 7, ii = l & 127;
            int t = t0 + tt, i = i0 + ii;
            smem[tt * 132 + ii] = (t < NT && i < NP) ? fusedM[(size_t)t * NP + i] : 0.f;
        }
        __syncthreads();
        int octl = tid >> 4, tl = tid & 15;
        bf16x8 v;
        #pragma unroll
        for (int e = 0; e < 8; ++e)
            v[e] = f2bf(smem[tl * 132 + octl * 8 + e]);
        size_t oct = i0 / 8 + octl;
        *reinterpret_cast<bf16x8*>(fMb + (oct * 1024 + t0 + tl) * 8) = v;
    } else if (blk < 677) {
        int idx = (blk - 640) * 256 + tid;
        if (idx < 48 + B * 600 + B * 300 + B * DD) zero_region[idx] = 0.f;
    } else if (blk < 933) {
        int idx = (blk - 677) * 256 + tid;
        qcb_zero[idx] = 0.f;
    } else {
        gcn_layer_body(drug_ver, adj, W0, b0, y0, DV, blk - 933, tid,
                       smem, smem + 64);
    }
}

// ---------------------------------------------------------------------------
// K2: prot GEMM (250, full-N tiles) + gcn_layer1 (448).  Grid 698.
__global__ __launch_bounds__(256) void k2_kernel(
    const float* __restrict__ prot_data, const short* __restrict__ Wb1,
    const float* __restrict__ b_prot, float* __restrict__ prot,
    const float* __restrict__ y0, const float* __restrict__ adj,
    const float* __restrict__ W1, const float* __restrict__ b1,
    float* __restrict__ y1) {
    __shared__ float smem[320];
    int blk = blockIdx.x, tid = threadIdx.x;
    if (blk < 250)
        gemm_body256<false>(prot_data, Wb1, b_prot, prot, DP, blk, tid);
    else
        gcn_layer_body(y0, adj, W1, b1, y1, DD, blk - 250, tid, smem, smem + 64);
}

// K3: qp GEMM (250, full-N tiles) + gcn_tail (448).  Grid 698.
__global__ __launch_bounds__(256) void k3_kernel(
    const float* __restrict__ prot, const short* __restrict__ Wb2,
    const float* __restrict__ bjp, float* __restrict__ qp,
    const float* __restrict__ y1, const float* __restrict__ adj,
    const float* __restrict__ W2, const float* __restrict__ b2,
    const float* __restrict__ Wf, const float* __restrict__ bf,
    const float* __restrict__ Wjc, const float* __restrict__ bjc,
    float* __restrict__ comp, short* __restrict__ qcb) {
    __shared__ float smem[320];
    int blk = blockIdx.x, tid = threadIdx.x;
    if (blk < 250)
        gemm_body256<true>(prot, Wb2, bjp, qp, DD, blk, tid);
    else
        gcn_tail_body(y1, adj, W2, b2, Wf, bf, Wjc, bjc, comp, qcb,
                      blk - 250, tid, smem, smem + 64);
}

// ---------------------------------------------------------------------------
// inter via MFMA. Grid 128.
__global__ __launch_bounds__(256) void inter_mfma_kernel(
    const float* __restrict__ qp, const short* __restrict__ qcb,
    const float* __restrict__ prot_inter, const float* __restrict__ exist,
    float* __restrict__ inter, float* __restrict__ s_bi,
    short* __restrict__ iTb, float* __restrict__ accums) {
    __shared__ float wred[4][4];
    int blk = blockIdx.x;
    int b = blk >> 4, mt = blk & 15;
    int tid = threadIdx.x;
    int lane = tid & 63, w = tid >> 6;
    int m0 = mt * 64 + w * 16;
    int lrow = lane & 15, lk = lane >> 4;
    f32x4 acc[4] = {{0.f,0.f,0.f,0.f},{0.f,0.f,0.f,0.f},
                    {0.f,0.f,0.f,0.f},{0.f,0.f,0.f,0.f}};
    int rowi = m0 + lrow;
    int rowc = (rowi < NP) ? rowi : (NP - 1);
    const float* arow = qp + ((size_t)b * NP + rowc) * DD + lk * 8;
    f32x4 a0 = *reinterpret_cast<const f32x4*>(arow);
    f32x4 a1 = *reinterpret_cast<const f32x4*>(arow + 4);
    for (int k0 = 0; k0 < DD; k0 += 32) {
        f32x4 c0 = a0, c1 = a1;
        if (k0 + 32 < DD) {
            a0 = *reinterpret_cast<const f32x4*>(arow + k0 + 32);
            a1 = *reinterpret_cast<const f32x4*>(arow + k0 + 36);
        }
        bf16x8 af;
        #pragma unroll
        for (int e = 0; e < 4; ++e) {
            af[e] = f2bf(c0[e]); af[4 + e] = f2bf(c1[e]);
        }
        const short* bb = qcb + (((size_t)b * 32 + (k0 >> 3) + lk) * 64 + lrow) * 8;
        #pragma unroll
        for (int nt = 0; nt < 4; ++nt) {
            bf16x8 bf = *reinterpret_cast<const bf16x8*>(bb + nt * 128);
            acc[nt] = __builtin_amdgcn_mfma_f32_16x16x32_bf16(af, bf, acc[nt], 0, 0, 0);
        }
    }
    float ex = exist[b];
    float aV = 0.f, aA = 0.f, aC = 0.f, aD = 0.f;
    float rowsq[4] = {0.f, 0.f, 0.f, 0.f};
    #pragma unroll
    for (int nt = 0; nt < 4; ++nt) {
        int j = nt * 16 + lrow;
        bool jv = (j < NK);
        #pragma unroll
        for (int r = 0; r < 4; ++r) {
            int i = m0 + lk * 4 + r;
            bool iv = (i < NP);
            float v = 0.f, lab = 0.f;
            if (jv) {
                if (iv) {
                    v = 1.f / (1.f + __expf(-acc[nt][r]));
                    lab = ex * prot_inter[((size_t)b * NP + i) * NK + j];
                    inter[((size_t)b * NP + i) * NK + j] = v;
                }
                iTb[(((size_t)(i >> 3) * 448 + b * NK + j) << 3) + (i & 7)] = f2bf(v);
            }
            aV += v; aA += v * v; aC += v * lab; aD += lab * lab;
            rowsq[r] += v * v;
        }
    }
    #pragma unroll
    for (int r = 0; r < 4; ++r) {
        float rs = rowsq[r];
        rs += __shfl_xor(rs, 1); rs += __shfl_xor(rs, 2);
        rs += __shfl_xor(rs, 4); rs += __shfl_xor(rs, 8);
        int i = m0 + lk * 4 + r;
        if (lrow == 0 && i < NP) s_bi[(size_t)b * NP + i] = rs;
    }
    #pragma unroll
    for (int off = 32; off; off >>= 1) {
        aV += __shfl_down(aV, off);
        aA += __shfl_down(aA, off);
        aC += __shfl_down(aC, off);
        aD += __shfl_down(aD, off);
    }
    if (lane == 0) {
        wred[w][0] = aV; wred[w][1] = aA; wred[w][2] = aC; wred[w][3] = aD;
    }
    __syncthreads();
    if (tid < 4) {
        float s = wred[0][tid] + wred[1][tid] + wred[2][tid] + wred[3][tid];
        atomicAdd(&accums[tid * 8 + b], s);
    }
}

// ---------------------------------------------------------------------------
// K5: cp_partial (1000) + fused MFMA (112).  Grid 1112.
__global__ __launch_bounds__(256) void k5_kernel(
    const float* __restrict__ prot, const float* __restrict__ comp,
    const float* __restrict__ inter, float* __restrict__ cp,
    const short* __restrict__ iTb, const short* __restrict__ fMb,
    float* __restrict__ fusedAbs) {
    __shared__ float irow[8][NK];
    __shared__ float sb[8];
    int blk = blockIdx.x, tid = threadIdx.x;
    if (blk < 1000) {
        int b = blk / 125, chunk = blk % 125;
        int d = tid;
        float creg[NK];
        #pragma unroll
        for (int k = 0; k < NK; ++k)
            creg[k] = comp[((size_t)b * NK + k) * DD + d];
        for (int l = tid; l < 8 * NK; l += 256) {
            int ii = l / NK, k = l % NK;
            irow[ii][k] = inter[((size_t)b * NP + chunk * 8 + ii) * NK + k];
        }
        const float C2LOG2E = 2.8853900817779268f;
        float p2l[8];
        #pragma unroll
        for (int ii = 0; ii < 8; ++ii)
            p2l[ii] = C2LOG2E * prot[((size_t)b * NP + chunk * 8 + ii) * DD + d];
        __syncthreads();
        float acc0 = 0.f, acc1 = 0.f;
        #pragma unroll 1
        for (int ii = 0; ii < 8; ++ii) {
            float p = p2l[ii];
            #pragma unroll
            for (int k = 0; k < NK; k += 2) {
                float e0 = __builtin_amdgcn_exp2f(p * creg[k]);
                float e1 = __builtin_amdgcn_exp2f(p * creg[k + 1]);
                float r0 = __builtin_amdgcn_rcpf(e0 + 1.f);
                float r1 = __builtin_amdgcn_rcpf(e1 + 1.f);
                acc0 = fmaf(fmaf(-2.f, r0, 1.f), irow[ii][k],     acc0);
                acc1 = fmaf(fmaf(-2.f, r1, 1.f), irow[ii][k + 1], acc1);
            }
        }
        atomicAdd(&cp[(size_t)b * DD + d], acc0 + acc1);
    } else {
        int fblk = blk - 1000;
        int mb = fblk % 14, nb = fblk / 14;
        int lane = tid & 63, w = tid >> 6;
        if (tid < 8) sb[tid] = 0.f;
        __syncthreads();
        int m0 = mb * 32 + (w >> 1) * 16;
        int n0 = nb * 128 + (w & 1) * 64;
        int lrow = lane & 15, lk = lane >> 4;
        f32x4 acc[4] = {{0.f,0.f,0.f,0.f},{0.f,0.f,0.f,0.f},
                        {0.f,0.f,0.f,0.f},{0.f,0.f,0.f,0.f}};
        for (int koct0 = 0; koct0 < 128; koct0 += 4) {
            int koct = koct0 + lk;
            bf16x8 af = *reinterpret_cast<const bf16x8*>(
                iTb + ((size_t)koct * 448 + m0 + lrow) * 8);
            const short* bb = fMb + ((size_t)koct * 1024 + n0 + lrow) * 8;
            #pragma unroll
            for (int nt = 0; nt < 4; ++nt) {
                bf16x8 bf = *reinterpret_cast<const bf16x8*>(bb + nt * 128);
                acc[nt] = __builtin_amdgcn_mfma_f32_16x16x32_bf16(af, bf, acc[nt], 0, 0, 0);
            }
        }
        #pragma unroll
        for (int r = 0; r < 4; ++r) {
            float part = fabsf(acc[0][r]) + fabsf(acc[1][r]) +
                         fabsf(acc[2][r]) + fabsf(acc[3][r]);
            #pragma unroll
            for (int off = 1; off < 16; off <<= 1)
                part += __shfl_xor(part, off);
            if (lrow == 0) {
                int row = m0 + lk * 4 + r;
                atomicAdd(&sb[row / NK], part);
            }
        }
        __syncthreads();
        if (tid < 8 && sb[tid] != 0.f) atomicAdd(&fusedAbs[tid], sb[tid]);
    }
}

// ---------------------------------------------------------------------------
// K6: fc1-with-inline-conv (160) + group (2000).  Grid 2160.
__global__ __launch_bounds__(256) void k6_kernel(
    const float* __restrict__ cp, const float* __restrict__ accums,
    const float* __restrict__ conv_w, const float* __restrict__ conv_b,
    const float* __restrict__ W, float* __restrict__ raw,
    const float* __restrict__ contacts, const float* __restrict__ s_bi,
    float* __restrict__ groupv) {
    int blk = blockIdx.x, t = threadIdx.x;
    if (blk < 160) {
        const int N = 600, kchunk = 128;
        int ot = blk / 16, ks = blk % 16;
        int ol = t & 63;
        int o = ot * 64 + ol;
        int w = t >> 6;
        int kbeg = ks * kchunk;
        __shared__ float xS[B][258];
        __shared__ float sin_[B][128];
        for (int l = t; l < B * DD; l += 256) {
            int b = l >> 8, d = l & 255;
            xS[b][d + 1] = cp[(size_t)b * DD + d] / accums[b];
        }
        if (t < B) { xS[t][0] = 0.f; xS[t][257] = 0.f; }
        __syncthreads();
        for (int l = t; l < B * kchunk; l += 256) {
            int b = l >> 7, kl = l & 127;
            int kg = kbeg + kl;
            int oo = kg >> 5, p = kg & 31;
            float w0 = conv_w[oo * 4 + 0], w1 = conv_w[oo * 4 + 1];
            float w2 = conv_w[oo * 4 + 2], w3 = conv_w[oo * 4 + 3];
            float cb = conv_b[oo];
            float m = -INFINITY;
            #pragma unroll
            for (int q = 0; q < 4; ++q) {
                int base = (p * 4 + q) * 2;
                float acc = cb;
                acc = fmaf(xS[b][base + 0], w0, acc);
                acc = fmaf(xS[b][base + 1], w1, acc);
                acc = fmaf(xS[b][base + 2], w2, acc);
                acc = fmaf(xS[b][base + 3], w3, acc);
                acc = (acc > 0.f) ? acc : 0.1f * acc;
                m = fmaxf(m, acc);
            }
            sin_[b][kl] = m;
        }
        __syncthreads();
        float acc[B];
        #pragma unroll
        for (int b = 0; b < B; ++b) acc[b] = 0.f;
        for (int k = kbeg + w; k < kbeg + kchunk; k += 4) {
            float wv = W[(size_t)k * N + o];
            int kl = k - kbeg;
            #pragma unroll
            for (int b = 0; b < B; ++b)
                acc[b] = fmaf(sin_[b][kl], wv, acc[b]);
        }
        __shared__ float red[4][64][B];
        #pragma unroll
        for (int b = 0; b < B; ++b) red[w][ol][b] = acc[b];
        __syncthreads();
        for (int p = t; p < 64 * B; p += 256) {
            int oo = p / B, b = p % B;
            int o2 = ot * 64 + oo;
            float s = red[0][oo][b] + red[1][oo][b] + red[2][oo][b] + red[3][oo][b];
            atomicAdd(&raw[(size_t)b * N + o2], s);
        }
    } else {
        int w = t >> 6, lane = t & 63;
        int gk = (blk - 160) * 4 + w;
        int b = gk / NP;
        const f32x4* row4 = reinterpret_cast<const f32x4*>(
            contacts + (size_t)gk * NP);
        const f32x4* sv4 = reinterpret_cast<const f32x4*>(s_bi + (size_t)b * NP);
        f32x4 z = {0.f, 0.f, 0.f, 0.f};
        f32x4 c0 = row4[lane];
        f32x4 c1 = row4[lane + 64];
        f32x4 c2 = row4[lane + 128];
        f32x4 c3 = z, s3 = z;
        f32x4 s0 = sv4[lane];
        f32x4 s1 = sv4[lane + 64];
        f32x4 s2 = sv4[lane + 128];
        if (lane + 192 < 250) { c3 = row4[lane + 192]; s3 = sv4[lane + 192]; }
        float g0 = 0.f, g1 = 0.f, g2 = 0.f, g3 = 0.f;
        #pragma unroll
        for (int e = 0; e < 4; ++e) {
            g0 = fmaf(c0[e], s0[e], g0);
            g1 = fmaf(c1[e], s1[e], g1);
            g2 = fmaf(c2[e], s2[e], g2);
            g3 = fmaf(c3[e], s3[e], g3);
        }
        float r0 = (c0[0] + c0[1]) + (c0[2] + c0[3]);
        float r1 = (c1[0] + c1[1]) + (c1[2] + c1[3]);
        float r2 = (c2[0] + c2[1]) + (c2[2] + c2[3]);
        float r3 = (c3[0] + c3[1]) + (c3[2] + c3[3]);
        float g = (g0 + g1) + (g2 + g3);
        float rs = (r0 + r1) + (r2 + r3);
        #pragma unroll
        for (int off = 32; off; off >>= 1) {
            g += __shfl_down(g, off);
            rs += __shfl_down(rs, off);
        }
        if (lane == 0) {
            float val;
            if (g == 0.f) val = sqrtf(1e10f) * sqrtf(rs);
            else          val = sqrtf(g) / accums[b] * sqrtf(rs);
            groupv[gk] = val;
        }
    }
}

// ---------------------------------------------------------------------------
// fc2 partial: staging applies bias+leaky to raw1.
__global__ __launch_bounds__(256) void fc2_kernel(
    const float* __restrict__ raw1, const float* __restrict__ b_r1,
    const float* __restrict__ W, float* __restrict__ raw2) {
    const int K = 600, N = 300, kchunk = 75;
    int t = threadIdx.x;
    int ol = t & 63;
    int o = blockIdx.x * 64 + ol;
    int w = t >> 6;
    int kbeg = blockIdx.y * kchunk;
    __shared__ float sin_[B][128];
    for (int l = t; l < B * kchunk; l += 256) {
        int b = l / kchunk, k = l % kchunk;
        float v = raw1[(size_t)b * K + kbeg + k] + b_r1[kbeg + k];
        v = (v > 0.f) ? v : 0.1f * v;
        sin_[b][k] = v;
    }
    __syncthreads();
    float acc[B];
    #pragma unroll
    for (int b = 0; b < B; ++b) acc[b] = 0.f;
    if (o < N) {
        for (int k = kbeg + w; k < kbeg + kchunk; k += 4) {
            float wv = W[(size_t)k * N + o];
            int kl = k - kbeg;
            #pragma unroll
            for (int b = 0; b < B; ++b)
                acc[b] = fmaf(sin_[b][kl], wv, acc[b]);
        }
    }
    __shared__ float red[4][64][B];
    #pragma unroll
    for (int b = 0; b < B; ++b) red[w][ol][b] = acc[b];
    __syncthreads();
    for (int p = t; p < 64 * B; p += 256) {
        int oo = p / B, b = p % B;
        int o2 = blockIdx.x * 64 + oo;
        if (o2 < N) {
            float s = red[0][oo][b] + red[1][oo][b] + red[2][oo][b] + red[3][oo][b];
            atomicAdd(&raw2[(size_t)b * N + o2], s);
        }
    }
}

// ---------------------------------------------------------------------------
// final: inline fc3 + groupv sum + assembly.
__global__ __launch_bounds__(256) void final_kernel(
    const float* __restrict__ accums, const float* __restrict__ groupv,
    const float* __restrict__ raw2, const float* __restrict__ b_r2,
    const float* __restrict__ W3, const float* __restrict__ b3,
    const float* __restrict__ label, float* __restrict__ out) {
    int tid = threadIdx.x;
    __shared__ float affnS[8];
    {
        int b = tid >> 5, k0 = tid & 31;
        float acc = 0.f;
        for (int k = k0; k < 300; k += 32) {
            float v = raw2[(size_t)b * 300 + k] + b_r2[k];
            v = (v > 0.f) ? v : 0.1f * v;
            acc = fmaf(v, W3[k], acc);
        }
        #pragma unroll
        for (int off = 16; off; off >>= 1) acc += __shfl_down(acc, off);
        if (k0 == 0) affnS[b] = acc + b3[0];
    }
    float s = 0.f;
    for (int l = tid; l < B * NP; l += 256) s += groupv[l];
    __shared__ float r[256];
    r[tid] = s;
    __syncthreads();
    for (int st = 128; st; st >>= 1) {
        if (tid < st) r[tid] += r[tid + st];
        __syncthreads();
    }
    if (tid == 0) {
        float gtot = r[0];
        float l0 = 0.f, l1 = 0.f, l2 = 0.f;
        for (int b = 0; b < B; ++b) {
            float S = accums[b];
            float A = accums[8 + b], C = accums[16 + b], D = accums[24 + b];
            float fA = accums[32 + b];
            l0 += 1.f + fA / S;
            float bind = A / (S * S) - 2.f * C / S + D;
            l1 += sqrtf(fmaxf(bind, 0.f));
            float dd = affnS[b] - label[b];
            l2 += dd * dd;
        }
        out[0] = (l0 + gtot + l1 + l2) * 0.125f;
    }
}

// ---------------------------------------------------------------------------
extern "C" void kernel_launch(void* const* d_in, const int* in_sizes, int n_in,
                              void* d_out, int out_size, void* d_ws, size_t ws_size,
                              hipStream_t stream) {
    const float* prot_data   = (const float*)d_in[0];
    const float* drug_ver    = (const float*)d_in[1];
    const float* drug_adj    = (const float*)d_in[2];
    const float* contacts    = (const float*)d_in[3];
    const float* prot_inter  = (const float*)d_in[4];
    const float* exist       = (const float*)d_in[5];
    const float* label       = (const float*)d_in[6];
    const float* fused       = (const float*)d_in[7];
    const float* W_prot      = (const float*)d_in[8];
    const float* b_prot      = (const float*)d_in[9];
    const float* gcn_W0      = (const float*)d_in[10];
    const float* gcn_b0      = (const float*)d_in[11];
    const float* gcn_W1      = (const float*)d_in[12];
    const float* gcn_b1      = (const float*)d_in[13];
    const float* gcn_W2      = (const float*)d_in[14];
    const float* gcn_b2      = (const float*)d_in[15];
    const float* gcn_Wf      = (const float*)d_in[16];
    const float* gcn_bf      = (const float*)d_in[17];
    const float* Wjp         = (const float*)d_in[18];
    const float* bjp         = (const float*)d_in[19];
    const float* Wjc         = (const float*)d_in[20];
    const float* bjc         = (const float*)d_in[21];
    const float* conv_w      = (const float*)d_in[22];
    const float* conv_b      = (const float*)d_in[23];
    const float* W_r1        = (const float*)d_in[24];
    const float* b_r1        = (const float*)d_in[25];
    const float* W_r2        = (const float*)d_in[26];
    const float* b_r2        = (const float*)d_in[27];
    const float* W_r3        = (const float*)d_in[28];
    const float* b_r3        = (const float*)d_in[29];

    float* ws = (float*)d_ws;
    size_t off = 0;
    auto alloc = [&](size_t n) { float* p = ws + off; off += n; return p; };
    float* prot     = alloc((size_t)B * NP * DD);
    float* qp       = alloc((size_t)B * NP * DD);
    float* tbuf     = alloc((size_t)B * NK * DD);   // y0; +ybuf = iTb alias
    float* ybuf     = alloc((size_t)B * NK * DD);   // y1
    float* comp     = alloc((size_t)B * NK * DD);
    float* qcbF     = alloc((size_t)65536);         // qcb bf16 [8][32][64][8]
    float* inter    = alloc((size_t)B * NP * NK);
    float* s_bi     = alloc((size_t)B * NP);
    float* groupv   = alloc((size_t)B * NP);
    short* Wb1      = (short*)alloc((DP / 8) * DD * 8 / 2);
    short* Wb2      = (short*)alloc((DD / 8) * DD * 8 / 2);
    short* fMb      = (short*)alloc((size_t)128 * 1024 * 8 / 2);
    // zero region: accums(48) + raw1(4800) + raw2(2400) + cp(2048)
    float* accums   = alloc(48);
    float* raw1     = alloc((size_t)B * 600);
    float* raw2     = alloc((size_t)B * 300);
    float* cp       = alloc((size_t)B * DD);

    short* qcb = (short*)qcbF;
    short* iTb = (short*)tbuf;
    (void)ybuf;

    // 1. prep (+gcn layer0)
    k1_kernel<<<1381, 256, 0, stream>>>(W_prot, Wb1, Wjp, Wb2, fused, fMb,
                                        accums, qcbF, drug_ver, drug_adj,
                                        gcn_W0, gcn_b0, tbuf);

    // 2. prot GEMM + gcn layer1
    k2_kernel<<<698, 256, 0, stream>>>(prot_data, Wb1, b_prot, prot,
                                       tbuf, drug_adj, gcn_W1, gcn_b1, ybuf);

    // 3. qp GEMM + gcn tail (emits qcb bf16)
    k3_kernel<<<698, 256, 0, stream>>>(prot, Wb2, bjp, qp,
                                       ybuf, drug_adj, gcn_W2, gcn_b2,
                                       gcn_Wf, gcn_bf, Wjc, bjc, comp, qcb);

    // 4. inter via MFMA (+ moments, s_bi, iTb)
    inter_mfma_kernel<<<128, 256, 0, stream>>>(
        qp, qcb, prot_inter, exist, inter, s_bi, iTb, accums);

    // 5. cp partial + fused MFMA
    k5_kernel<<<1112, 256, 0, stream>>>(prot, comp, inter, cp,
                                        iTb, fMb, accums + 32);

    // 6. fc1(conv inline) + group (overlapped)
    k6_kernel<<<2160, 256, 0, stream>>>(cp, accums, conv_w, conv_b, W_r1, raw1,
                                        contacts, s_bi, groupv);

    // 7. fc2
    fc2_kernel<<<dim3(5, 8), 256, 0, stream>>>(raw1, b_r1, W_r2, raw2);

    // 8. final loss
    final_kernel<<<1, 256, 0, stream>>>(accums, groupv, raw2, b_r2,
                                        W_r3, b_r3, label, (float*)d_out);
}